// Round 3
// baseline (571.846 us; speedup 1.0000x reference)
//
#include <hip/hip_runtime.h>

// B=4, S=4096, H=512, K=2, D=8, experts=64
// T = 16384 tokens; out: [8, 32768, 512] fp32 = 512 MiB
#define NDEV    8
#define TOK     16384
#define TKROWS  (TOK * 2)                 // 32768 (token,k) rows
#define COLS    128                       // float4 per row (H=512)
#define SECT    ((size_t)TKROWS * COLS)   // 4,194,304 f4 per device section

// Output-centric decomposition: 8192 blocks x 256 threads, each block owns a
// CONTIGUOUS 64 KiB output segment (4096 f4) inside ONE device section.
// 1024 blocks per section (1024 * 4096 = SECT).
#define CHUNK_F4   4096                   // f4 per block
#define NBLOCKS    8192

typedef float f4 __attribute__((ext_vector_type(4)));

// Round-3 change: write pattern restructured to match the rocclr fill kernel
// (the only thing measured at 6.2 TB/s on this buffer). Previous kernel had
// each wave scatter 8 x 1 KiB at 64 MiB stride + a read mixed in -> ~2.8 TB/s.
// Now each block emits one sequential 64 KiB write stream; the routing test
// (dev == d) is wave-uniform, and the 7/8 non-matching waves are pure
// write-only (no x fetch at all). x is read exactly once per (t,k).
__global__ __launch_bounds__(256)
void a2a_dispatch_kernel(const f4*  __restrict__ x,     // [TOK, COLS]
                         const int* __restrict__ eidx,  // [TKROWS]
                         const int* __restrict__ emap,  // [64]
                         f4*        __restrict__ out)   // [NDEV, TKROWS, COLS]
{
    const int tid = threadIdx.x;
    const int b   = blockIdx.x;                 // [0, 8192)
    const int d   = b >> 10;                    // device section of this block
    const int lbase = (b & 1023) * CHUNK_F4;    // section-local f4 base
    f4* __restrict__ sec = out + (size_t)d * SECT;

#pragma unroll
    for (int j = 0; j < 16; ++j) {
        const int idx = lbase + j * 256 + tid;  // section-local f4 index
        const int col = idx & (COLS - 1);
        const int tk  = idx >> 7;               // (token,k) row
        const int t   = tk >> 1;                // token id (K=2)

        // Wave-uniform: 64 lanes span one half-row of one tk.
        const int dev = emap[eidx[tk]];

        f4 v = {0.f, 0.f, 0.f, 0.f};
        if (dev == d)                            // wave-uniform branch
            v = x[(size_t)t * COLS + col];

        sec[idx] = v;                            // sequential 4 KiB block-store
    }
}

extern "C" void kernel_launch(void* const* d_in, const int* in_sizes, int n_in,
                              void* d_out, int out_size, void* d_ws, size_t ws_size,
                              hipStream_t stream) {
    const f4*  x    = (const f4*)d_in[0];
    const int* eidx = (const int*)d_in[1];
    const int* emap = (const int*)d_in[2];
    f4*        out  = (f4*)d_out;

    // No memset prepass: every output line is written exactly once by the
    // kernel. (The recurring 2.147 GB fillBufferAligned dispatches in the
    // profile are the harness's per-iteration poison, outside our control.)
    a2a_dispatch_kernel<<<NBLOCKS, 256, 0, stream>>>(x, eidx, emap, out);
}

// Round 4
// 568.333 us; speedup vs baseline: 1.0062x; 1.0062x over previous
//
#include <hip/hip_runtime.h>

// B=4, S=4096, H=512, K=2, D=8, experts=64
// T = 16384 tokens; out: [8, 32768, 512] fp32 = 512 MiB
#define NDEV    8
#define TOK     16384
#define TKROWS  (TOK * 2)                 // 32768 (token,k) rows
#define COLS    128                       // float4 per row (H=512)
#define SECT    (TKROWS * COLS)           // 4,194,304 f4 per device section (1<<22)
#define TOTAL   (NDEV * SECT)             // 33,554,432 f4 total (1<<25)

#define NBLOCKS  2048                     // = 256 CUs x 8 blocks/CU (max residency)
#define NTHREADS (NBLOCKS * 256)          // 524,288 (1<<19)
#define ITERS    (TOTAL / NTHREADS)       // 64

typedef float f4 __attribute__((ext_vector_type(4)));

// Round-4 change: grid-stride in FLAT OUTPUT ORDER — the exact access shape
// of the rocclr fill kernel (the only code measured at 6.2 TB/s on this
// buffer). All 524K resident threads write one dense contiguous 8 MiB front
// per iteration, rolling linearly through the 512 MiB output -> each HBM
// bank sees one long row-buffer hit streak.
//
// Previous structures all row-thrashed HBM (~2.4-2.8 TB/s):
//   r1/r2: 8 concurrent fronts at 64 MiB power-of-2 stride (same banks,
//          different rows, ping-pong every burst);
//   r3:    2048 independent sequential 64 KiB streams (4+ open rows/bank).
//
// Routing test stays wave-uniform (64 lanes = half of one tk row). eidx
// (128 KB) and emap (256 B) are L2-resident; x (32 MiB) is L3-resident.
__global__ __launch_bounds__(256)
void a2a_dispatch_kernel(const f4*  __restrict__ x,     // [TOK, COLS]
                         const int* __restrict__ eidx,  // [TKROWS]
                         const int* __restrict__ emap,  // [64]
                         f4*        __restrict__ out)   // flat [TOTAL]
{
    const unsigned base = blockIdx.x * 256 + threadIdx.x;   // [0, NTHREADS)

#pragma unroll 4
    for (int it = 0; it < ITERS; ++it) {
        const unsigned idx   = base + (unsigned)it * NTHREADS; // flat f4 index
        const unsigned d     = idx >> 22;            // device section
        const unsigned local = idx & (SECT - 1);     // index within section
        const unsigned tk    = local >> 7;           // (token,k) row
        const unsigned col   = local & (COLS - 1);
        const unsigned t     = tk >> 1;              // token id (K=2)

        // Wave-uniform per row: 64 lanes span one half-row of one tk.
        const unsigned dev = (unsigned)emap[eidx[tk]];

        f4 v = {0.f, 0.f, 0.f, 0.f};
        if (dev == d)                                // wave-uniform branch
            v = x[t * COLS + col];

        out[idx] = v;                                // dense rolling front
    }
}

extern "C" void kernel_launch(void* const* d_in, const int* in_sizes, int n_in,
                              void* d_out, int out_size, void* d_ws, size_t ws_size,
                              hipStream_t stream) {
    const f4*  x    = (const f4*)d_in[0];
    const int* eidx = (const int*)d_in[1];
    const int* emap = (const int*)d_in[2];
    f4*        out  = (f4*)d_out;

    // No memset prepass: every output line is written exactly once by the
    // kernel. (The recurring 2.147 GB fillBufferAligned dispatches in the
    // profile are the harness's per-iteration poison, outside our control.)
    a2a_dispatch_kernel<<<NBLOCKS, 256, 0, stream>>>(x, eidx, emap, out);
}

// Round 5
// 560.817 us; speedup vs baseline: 1.0197x; 1.0134x over previous
//
#include <hip/hip_runtime.h>

// B=4, S=4096, H=512, K=2, D=8, experts=64
// T = 16384 tokens; out: [8, 32768, 512] fp32 = 512 MiB
#define NDEV    8
#define TOK     16384
#define TKROWS  (TOK * 2)                 // 32768 (token,k) rows
#define COLS    128                       // float4 per row (H=512)
#define SECT    (TKROWS * COLS)           // 4,194,304 f4 per device section

#define ROWS_PER_BLK 32
#define CHUNK_F4     (ROWS_PER_BLK * COLS)     // 4096 f4 = 64 KiB per block
#define BLKS_PER_DEV (TKROWS / ROWS_PER_BLK)   // 1024
#define NBLOCKS      (NDEV * BLKS_PER_DEV)     // 8192

typedef float f4 __attribute__((ext_vector_type(4)));

// Round-5 change: REMOVE ALL LOADS FROM THE STORE LOOP.
// r1-r4 post-mortem: four different store patterns all ~2.5 TB/s -> the
// invariant was the per-iteration routing chain (eidx->emap->select) inside
// the store loop. Loads and stores share vmcnt on CDNA; every s_waitcnt to
// consume a routing load also drains all older outstanding stores, so the
// store pipeline never fills. The rocclr fill (6.2 TB/s) has no loads.
//
// Structure: each block owns a 64 KiB tile (32 rows) in one device section.
//   prologue: 32 routing lookups -> __ballot -> one SGPR mask (per wave)
//   pass 1:   unconditional dense zero-fill of the tile (pure stores,
//             zero loads, zero waits — the fill kernel's exact inner loop)
//   pass 2:   overwrite the ~32/8=4 matching rows with token data while the
//             tile is still L2-dirty (2 MiB active/XCD < 4 MiB L2), so the
//             double-write coalesces in L2 — no extra HBM traffic.
__global__ __launch_bounds__(256)
void a2a_dispatch_kernel(const f4*  __restrict__ x,     // [TOK, COLS]
                         const int* __restrict__ eidx,  // [TKROWS]
                         const int* __restrict__ emap,  // [64]
                         f4*        __restrict__ out)   // [NDEV, TKROWS, COLS]
{
    const int tid = threadIdx.x;
    const int b   = blockIdx.x;                    // [0, 8192)
    const int d   = b >> 10;                       // device section
    const int tk0 = (b & 1023) * ROWS_PER_BLK;     // first tk row of tile
    f4* __restrict__ sec = out + (size_t)d * SECT + (size_t)tk0 * COLS;

    // Prologue: routing mask for this tile's 32 rows (each wave redundantly;
    // eidx is 128 KiB L2-resident, emap 256 B).
    const int lane = tid & 63;
    int match;
    {
        const int r   = lane & 31;
        const int dev = emap[eidx[tk0 + r]];
        match = (lane < 32) && (dev == d);
    }
    const unsigned mask = (unsigned)__ballot(match);   // bit r: row r is ours

    // Pass 1: dense 64 KiB zero-fill. No loads, no waitcnt in the loop —
    // stores stream at full vmcnt depth.
    const f4 z = {0.f, 0.f, 0.f, 0.f};
#pragma unroll
    for (int j = 0; j < 16; ++j)
        sec[j * 256 + tid] = z;

    __syncthreads();   // pass-2 overwrites must follow ALL pass-1 zeros

    // Pass 2: sparse data overwrite of matching rows (avg 4 per tile).
    // Row list is in an SGPR mask — still no loads feeding store addresses.
    unsigned m = mask;
    while (m) {
        const int r = __builtin_ctz(m);
        m &= m - 1;
        if (tid < 128) {                           // one 2 KiB row per iter
            const int t = (tk0 + r) >> 1;          // token id (K=2)
            sec[r * COLS + tid] = x[(size_t)t * COLS + tid];
        }
    }
}

extern "C" void kernel_launch(void* const* d_in, const int* in_sizes, int n_in,
                              void* d_out, int out_size, void* d_ws, size_t ws_size,
                              hipStream_t stream) {
    const f4*  x    = (const f4*)d_in[0];
    const int* eidx = (const int*)d_in[1];
    const int* emap = (const int*)d_in[2];
    f4*        out  = (f4*)d_out;

    // No memset prepass: pass 1 lays the zero background, pass 2 overlays
    // token data in-L2. (The 2.147 GB fillBufferAligned per iteration is the
    // harness's poison, in the timed window but outside our control.)
    a2a_dispatch_kernel<<<NBLOCKS, 256, 0, stream>>>(x, eidx, emap, out);
}

// Round 7
// 551.537 us; speedup vs baseline: 1.0368x; 1.0168x over previous
//
#include <hip/hip_runtime.h>

// B=4, S=4096, H=512, K=2, D=8, experts=64
// T = 16384 tokens; out: [8, 32768, 512] fp32 = 512 MiB
#define NDEV    8
#define TOK     16384
#define TKROWS  (TOK * 2)                 // 32768 (token,k) rows
#define COLS    128                       // float4 per row (H=512)
#define SECT    ((size_t)TKROWS * COLS)   // f4 per device section
#define LIVE_F4 (TKROWS * COLS)           // 4,194,304 live (tk,col) chunks

typedef float f4 __attribute__((ext_vector_type(4)));

// Round-7 = round-6 resubmit (round 6 died to a container-acquisition
// failure, no kernel signal). Rationale unchanged:
// r0 split (memset + scatter) is session best at 543 us; r1-r5 fused
// single-pass variants all ~2.5 TB/s on the 512 MiB write regardless of
// store structure, while the rocclr fill path sustains 6.2 TB/s on this
// exact buffer. So: zeros via hipMemsetAsync (fill engine), data via a
// minimal scatter touching only the 64 MiB of live rows, with 4-way ILP so
// the routing-load -> x-load -> store chains pipeline instead of stalling
// per element (r0 did one chain per thread).
__global__ __launch_bounds__(256)
void a2a_scatter_kernel(const f4*  __restrict__ x,     // [TOK, COLS]
                        const int* __restrict__ eidx,  // [TKROWS]
                        const int* __restrict__ emap,  // [64]
                        f4*        __restrict__ out)   // [NDEV, TKROWS, COLS]
{
    // 4096 blocks x 256 threads x 4 chunks = 4,194,304 = LIVE_F4
    const int base = (blockIdx.x * 256 + threadIdx.x) * 4;

    int tk[4], col[4], dev[4];
#pragma unroll
    for (int j = 0; j < 4; ++j) {
        const int idx = base + j;          // consecutive: same tk row (COLS=128)
        col[j] = idx & (COLS - 1);
        tk[j]  = idx >> 7;
        dev[j] = emap[eidx[tk[j]]];        // wave-uniform per row, L1-hot
    }

    f4 v[4];
#pragma unroll
    for (int j = 0; j < 4; ++j)
        v[j] = x[(size_t)(tk[j] >> 1) * COLS + col[j]];   // L3-resident read

#pragma unroll
    for (int j = 0; j < 4; ++j)
        out[(size_t)dev[j] * SECT + (size_t)tk[j] * COLS + col[j]] = v[j];
}

extern "C" void kernel_launch(void* const* d_in, const int* in_sizes, int n_in,
                              void* d_out, int out_size, void* d_ws, size_t ws_size,
                              hipStream_t stream) {
    const f4*  x    = (const f4*)d_in[0];
    const int* eidx = (const int*)d_in[1];
    const int* emap = (const int*)d_in[2];
    f4*        out  = (f4*)d_out;

    // Zero background via the rocclr fill path — the only code measured at
    // 6.2 TB/s on this buffer (512 MiB -> ~86 us). out_size is an element
    // count (r0: out_size*4 memset passed and fit the timing window).
    hipMemsetAsync(d_out, 0, (size_t)out_size * sizeof(float), stream);

    // Then overlay the 64 MiB of live token rows.
    const int block = 256;
    const int grid  = LIVE_F4 / (block * 4);   // 4096 blocks
    a2a_scatter_kernel<<<grid, block, 0, stream>>>(x, eidx, emap, out);
}